// Round 15
// baseline (143.576 us; speedup 1.0000x reference)
//
#include <hip/hip_runtime.h>

typedef __bf16 bf16x4 __attribute__((ext_vector_type(4)));
typedef __bf16 bf16x8 __attribute__((ext_vector_type(8)));
typedef float  f32x4  __attribute__((ext_vector_type(4)));

#define MFMA(a, b, c) __builtin_amdgcn_mfma_f32_16x16x32_bf16(a, b, c, 0, 0, 0)

static constexpr int kHeads = 8;
static constexpr int kS     = 4096;

#define CSC 0.18033688011112042f            // log2(e)/8 — folded into Q in qkv
#define LF  (13.287712379549449f / 32.0f)   // log2(10000)/32
#define INV2PI 0.15915494309189535f

__device__ inline float fexp2(float x) {
#if __has_builtin(__builtin_amdgcn_exp2f)
  return __builtin_amdgcn_exp2f(x);
#else
  return __expf(x * 0.6931471805599453f);
#endif
}
__device__ inline float fsin_rev(float rev) {
#if __has_builtin(__builtin_amdgcn_sinf)
  return __builtin_amdgcn_sinf(rev);
#else
  return __sinf(rev * 6.283185307179586f);
#endif
}
__device__ inline float fcos_rev(float rev) {
#if __has_builtin(__builtin_amdgcn_cosf)
  return __builtin_amdgcn_cosf(rev);
#else
  return __cosf(rev * 6.283185307179586f);
#endif
}

// fragment permutation within a 32-element k-block: elem d=16*hi+4*g+e -> slot 8*g+4*hi+e
__device__ inline int perm32(int d) {
  return (((d >> 2) & 3) << 3) + (((d >> 4) & 1) << 2) + (d & 3);
}

__device__ inline void gl16(const void* src, void* lds) {
  __builtin_amdgcn_global_load_lds(
      (const __attribute__((address_space(1))) unsigned int*)src,
      (__attribute__((address_space(3))) unsigned int*)lds, 16, 0, 0);
}

// ---------------------------------------------------------------------------
// wprep: fp32 weights [512 k][512 col] -> fragment-major bf16x8  (r7, proven)
// ---------------------------------------------------------------------------
__global__ __launch_bounds__(256) void wprep(
    const float* __restrict__ w0, const float* __restrict__ w1,
    const float* __restrict__ w2, __bf16* __restrict__ dstb) {
  const int kb32 = blockIdx.x, m = blockIdx.y;
  const float* W = (m == 0) ? w0 : (m == 1) ? w1 : w2;
  bf16x8* dst = (bf16x8*)dstb;
  for (int e = threadIdx.x; e < 2048; e += 256) {
    int lg = e >> 9, col = e & 511;
    bf16x8 v;
    #pragma unroll
    for (int j = 0; j < 8; ++j) {
      int k = kb32 * 32 + 4 * lg + (j & 3) + 16 * (j >> 2);
      v[j] = (__bf16)W[(size_t)k * 512 + col];
    }
    dst[(((size_t)m * 16 + kb32) * 4 + lg) * 512 + col] = v;
  }
}

// ---------------------------------------------------------------------------
// qkv: r12 version (fp32 x, direct W fragments, grid (128,4), 6 tiles/wave)
// ---------------------------------------------------------------------------
__global__ __launch_bounds__(256) void qkv(
    const float* __restrict__ x, const __bf16* __restrict__ Wqkvb,
    const float* __restrict__ bq, const float* __restrict__ bk,
    const float* __restrict__ bv,
    __bf16* __restrict__ Qb, __bf16* __restrict__ Kb, __bf16* __restrict__ Vt)
{
  const int tt   = blockIdx.x;
  const int hp   = blockIdx.y;
  const int wave = threadIdx.x >> 6;
  const int lane = threadIdx.x & 63;
  const int l15  = lane & 15;
  const int lg   = lane >> 4;

  const int tok0 = tt * 64 + wave * 16;
  const float* xrow = x + (size_t)(tok0 + l15) * 512;
  const bf16x8* Wf = (const bf16x8*)Wqkvb;

  f32x4 acc[6][4];   // [m*2+hh][cb]
  #pragma unroll
  for (int t = 0; t < 6; ++t)
    #pragma unroll
    for (int cb = 0; cb < 4; ++cb) acc[t][cb] = f32x4{0.f, 0.f, 0.f, 0.f};

  for (int kb32 = 0; kb32 < 16; ++kb32) {
    f32x4 xa  = *(const f32x4*)(xrow + kb32 * 32 + 4 * lg);
    f32x4 xb4 = *(const f32x4*)(xrow + kb32 * 32 + 16 + 4 * lg);
    bf16x8 af;
    af[0] = (__bf16)xa.x; af[1] = (__bf16)xa.y; af[2] = (__bf16)xa.z; af[3] = (__bf16)xa.w;
    af[4] = (__bf16)xb4.x; af[5] = (__bf16)xb4.y; af[6] = (__bf16)xb4.z; af[7] = (__bf16)xb4.w;
    #pragma unroll
    for (int t = 0; t < 6; ++t) {
      const int m = t >> 1, hh = t & 1;
      const int colb = (hp * 2 + hh) * 64;
      const bf16x8* wrow = Wf + (((size_t)m * 16 + kb32) * 4 + lg) * 512 + colb + l15;
      #pragma unroll
      for (int cb = 0; cb < 4; ++cb)
        acc[t][cb] = MFMA(af, wrow[cb * 16], acc[t][cb]);
    }
  }

  const float frrev0 = fexp2(-LF * (float)l15) * INV2PI;
  const float frrev1 = fexp2(-LF * (float)(16 + l15)) * INV2PI;
  float snv[4][2], csv[4][2];
  #pragma unroll
  for (int r = 0; r < 4; ++r) {
    float sp = (float)((tok0 + 4 * lg + r) & (kS - 1));
    #pragma unroll
    for (int cb = 0; cb < 2; ++cb) {
      float rev = sp * (cb == 0 ? frrev0 : frrev1);
      rev -= floorf(rev);
      snv[r][cb] = fsin_rev(rev);
      csv[r][cb] = fcos_rev(rev);
    }
  }

  #pragma unroll
  for (int t = 0; t < 6; ++t) {
    const int m = t >> 1, hh = t & 1;
    const int h = hp * 2 + hh;
    const float* bias = (m == 0) ? bq : (m == 1) ? bk : bv;
    #pragma unroll
    for (int cb = 0; cb < 4; ++cb) {
      float bv_ = bias[h * 64 + cb * 16 + l15];
      #pragma unroll
      for (int r = 0; r < 4; ++r) acc[t][cb][r] += bv_;
    }
    if (m < 2) {
      #pragma unroll
      for (int r = 0; r < 4; ++r)
        #pragma unroll
        for (int cb = 0; cb < 2; ++cb) {
          float rx = acc[t][cb][r], ry = acc[t][cb + 2][r];
          acc[t][cb][r]     = rx * csv[r][cb] - ry * snv[r][cb];
          acc[t][cb + 2][r] = rx * snv[r][cb] + ry * csv[r][cb];
        }
      if (m == 0) {
        #pragma unroll
        for (int cb = 0; cb < 4; ++cb)
          #pragma unroll
          for (int r = 0; r < 4; ++r) acc[t][cb][r] *= CSC;
      }
    }
    #pragma unroll
    for (int r = 0; r < 4; ++r) {
      int tok = tok0 + 4 * lg + r;
      int b = tok >> 12, srow = tok & (kS - 1);
      size_t bh = (size_t)(b * kHeads + h);
      #pragma unroll
      for (int cb = 0; cb < 4; ++cb) {
        int d = cb * 16 + l15;
        __bf16 v = (__bf16)acc[t][cb][r];
        if (m < 2) {
          int slot = (d & ~31) + perm32(d & 31);
          if (m == 0) Qb[(bh * kS + srow) * 64 + slot] = v;
          else        Kb[(bh * kS + srow) * 64 + slot] = v;
        } else {
          Vt[((size_t)bh * 64 + d) * kS + (srow & ~31) + perm32(srow & 31)] = v;
        }
      }
    }
  }
}

// ---------------------------------------------------------------------------
// attn: q-tile 32 PER WAVE (4 waves x 32 q = 128 q/block) -> each K/V LDS
//   fragment feeds 2 q-fragments: 32 MFMA per 16 ds_read_b128 (was 16:16).
//   Halves LDS-read bytes per FLOP (the measured wall).  3-buffer static
//   schedule, PV(t-1) pipelined vs exp(t), r5-proven 4-gl16 staging.
//   grid = 512 (XCD-swizzled), block = 256.
// ---------------------------------------------------------------------------
__global__ __launch_bounds__(256) void attn(
    const __bf16* __restrict__ Qb, const __bf16* __restrict__ Kb,
    const __bf16* __restrict__ Vt, __bf16* __restrict__ Ob)
{
  __shared__ __align__(16) char smem[49152];  // 3 bufs x (K 8KB + V 8KB)

  const int id   = blockIdx.x;
  const int bh   = ((id & 7) << 1) | ((id >> 3) & 1);
  const int qt   = id >> 4;                    // [0,32)
  const int tid  = threadIdx.x;
  const int wave = tid >> 6;
  const int lane = tid & 63;
  const int l15  = lane & 15;
  const int lg   = lane >> 4;

  const __bf16* Qp = Qb + (size_t)bh * kS * 64;
  const char*   Kp = (const char*)(Kb + (size_t)bh * kS * 64);
  const char*   Vp = (const char*)(Vt + (size_t)bh * 64 * kS);

  const int q0 = qt * 128 + wave * 32;

  bf16x8 qf[2][2];   // [qi][dh], q-rows q0 + qi*16 + l15
  #pragma unroll
  for (int qi = 0; qi < 2; ++qi)
    #pragma unroll
    for (int dh = 0; dh < 2; ++dh)
      qf[qi][dh] = *(const bf16x8*)(Qp + (size_t)(q0 + qi * 16 + l15) * 64 + dh * 32 + 8 * lg);

  // staging (r5-proven): 256 threads x (2 K-gl16 + 2 V-gl16) = 16KB/tile
  const int r0 = tid >> 3, c0 = tid & 7, r1 = r0 + 32;
  const char* ksrc0 = Kp + (size_t)r0 * 128 + ((16 * c0) ^ ((r0 & 7) << 4));
  const char* ksrc1 = Kp + (size_t)r1 * 128 + ((16 * c0) ^ ((r1 & 7) << 4));
  const char* vsrc0 = Vp + (size_t)r0 * 8192 + ((16 * c0) ^ ((r0 & 7) << 4));
  const char* vsrc1 = Vp + (size_t)r1 * 8192 + ((16 * c0) ^ ((r1 & 7) << 4));
  const int wb = wave * 1024;   // wave-uniform dests (HW adds lane*16)

  const int swz = (l15 & 7) << 4;
  const int ka0 = l15 * 128 + ((16 * lg) ^ swz);
  const int ka1 = l15 * 128 + ((64 + 16 * lg) ^ swz);
  const int va0 = 8192 + ka0;
  const int va1 = 8192 + ka1;

  const f32x4 kZero = f32x4{0.f, 0.f, 0.f, 0.f};

  char* const B0 = smem;
  char* const B1 = smem + 16384;
  char* const B2 = smem + 32768;

  f32x4 oacc[2][4];   // [qi][db]
  #pragma unroll
  for (int qi = 0; qi < 2; ++qi)
    #pragma unroll
    for (int db = 0; db < 4; ++db) oacc[qi][db] = kZero;
  float lp0 = 0.f, lp1 = 0.f;
  bf16x8 paP[2][2], paC[2][2];   // [qi][half]

  auto stage = [&](char* sb) {
    gl16(ksrc0, sb + wb);          gl16(ksrc1, sb + 4096 + wb);
    gl16(vsrc0, sb + 8192 + wb);   gl16(vsrc1, sb + 12288 + wb);
    ksrc0 += 8192; ksrc1 += 8192; vsrc0 += 128; vsrc1 += 128;
  };

  // prologue: stage tile 0 -> B0; sync; stage tile 1 -> B1; QK(0)+exp
  stage(B0);
  __syncthreads();
  stage(B1);
  {
    f32x4 sa[2][4];
    __builtin_amdgcn_s_setprio(1);
    #pragma unroll
    for (int kh = 0; kh < 4; ++kh) {
      bf16x8 kf0 = *(const bf16x8*)(B0 + kh * 2048 + ka0);
      bf16x8 kf1 = *(const bf16x8*)(B0 + kh * 2048 + ka1);
      #pragma unroll
      for (int qi = 0; qi < 2; ++qi) {
        sa[qi][kh] = MFMA(kf0, qf[qi][0], kZero);
        sa[qi][kh] = MFMA(kf1, qf[qi][1], sa[qi][kh]);
      }
    }
    __builtin_amdgcn_s_setprio(0);
    #pragma unroll
    for (int qi = 0; qi < 2; ++qi)
      #pragma unroll
      for (int kh = 0; kh < 4; ++kh)
        #pragma unroll
        for (int rr = 0; rr < 4; ++rr) {
          float p = fexp2(sa[qi][kh][rr]);
          if (qi == 0) lp0 += p; else lp1 += p;
          paP[qi][kh >> 1][(kh & 1) * 4 + rr] = (__bf16)p;
        }
  }

  auto body = [&](const char* sbP, const char* sbC, char* sbN, bool doStage) {
    __syncthreads();    // stage(t) complete; buf(t-3) reads long done
    if (doStage) stage(sbN);
    f32x4 sa[2][4];
    __builtin_amdgcn_s_setprio(1);
    #pragma unroll
    for (int kh = 0; kh < 4; ++kh) {
      bf16x8 kf0 = *(const bf16x8*)(sbC + kh * 2048 + ka0);
      bf16x8 kf1 = *(const bf16x8*)(sbC + kh * 2048 + ka1);
      #pragma unroll
      for (int qi = 0; qi < 2; ++qi) {
        sa[qi][kh] = MFMA(kf0, qf[qi][0], kZero);
        sa[qi][kh] = MFMA(kf1, qf[qi][1], sa[qi][kh]);
      }
    }
    // PV(t-1): independent of sa — grinds MFMA pipe while exp(t) runs on VALU
    #pragma unroll
    for (int db = 0; db < 4; ++db) {
      bf16x8 vf0 = *(const bf16x8*)(sbP + db * 2048 + va0);
      bf16x8 vf1 = *(const bf16x8*)(sbP + db * 2048 + va1);
      #pragma unroll
      for (int qi = 0; qi < 2; ++qi) {
        oacc[qi][db] = MFMA(vf0, paP[qi][0], oacc[qi][db]);
        oacc[qi][db] = MFMA(vf1, paP[qi][1], oacc[qi][db]);
      }
    }
    __builtin_amdgcn_s_setprio(0);
    #pragma unroll
    for (int qi = 0; qi < 2; ++qi)
      #pragma unroll
      for (int kh = 0; kh < 4; ++kh)
        #pragma unroll
        for (int rr = 0; rr < 4; ++rr) {
          float p = fexp2(sa[qi][kh][rr]);
          if (qi == 0) lp0 += p; else lp1 += p;
          paC[qi][kh >> 1][(kh & 1) * 4 + rr] = (__bf16)p;
        }
    #pragma unroll
    for (int qi = 0; qi < 2; ++qi) {
      paP[qi][0] = paC[qi][0];
      paP[qi][1] = paC[qi][1];
    }
  };

  // steady state: t = 1..60 (20 groups of 3) + peeled tail t = 61,62,63
  for (int g = 0; g < 20; ++g) {
    body(B0, B1, B2, true);
    body(B1, B2, B0, true);
    body(B2, B0, B1, true);
  }
  body(B0, B1, B2, true);
  body(B1, B2, B0, true);
  body(B2, B0, B1, false);

  // epilogue: PV(63) from B0
  {
    __builtin_amdgcn_s_setprio(1);
    #pragma unroll
    for (int db = 0; db < 4; ++db) {
      bf16x8 vf0 = *(const bf16x8*)(B0 + db * 2048 + va0);
      bf16x8 vf1 = *(const bf16x8*)(B0 + db * 2048 + va1);
      #pragma unroll
      for (int qi = 0; qi < 2; ++qi) {
        oacc[qi][db] = MFMA(vf0, paP[qi][0], oacc[qi][db]);
        oacc[qi][db] = MFMA(vf1, paP[qi][1], oacc[qi][db]);
      }
    }
    __builtin_amdgcn_s_setprio(0);
  }

  const int b = bh >> 3, h = bh & 7;
  #pragma unroll
  for (int qi = 0; qi < 2; ++qi) {
    float lrun = (qi == 0) ? lp0 : lp1;
    lrun += __shfl_xor(lrun, 16);
    lrun += __shfl_xor(lrun, 32);
    float inv = 1.0f / lrun;
    const int q = q0 + qi * 16 + l15;
    #pragma unroll
    for (int db = 0; db < 4; ++db) {
      bf16x4 o4;
      #pragma unroll
      for (int rr = 0; rr < 4; ++rr) o4[rr] = (__bf16)(oacc[qi][db][rr] * inv);
      size_t e = ((size_t)(b * kS + q)) * 512 + h * 64 + (db >> 1) * 32 + 8 * lg + 4 * (db & 1);
      *(bf16x4*)(Ob + e) = o4;
    }
  }
}

// ---------------------------------------------------------------------------
// oproj: out[t][m] = sum_c Ob[t][c] * wo[c][m] + wo_b[m]   (fp32 out)  (r7)
// ---------------------------------------------------------------------------
__global__ __launch_bounds__(256) void oproj(
    const __bf16* __restrict__ Ob, const __bf16* __restrict__ Wofb,
    const float* __restrict__ wob, float* __restrict__ out)
{
  const int tt   = blockIdx.x;
  const int ct   = blockIdx.y;
  const int wave = threadIdx.x >> 6;
  const int lane = threadIdx.x & 63;
  const int l15  = lane & 15;
  const int lg   = lane >> 4;

  const int tok0 = tt * 64 + wave * 16;
  const int colbase = ct * 64;
  const __bf16* orow = Ob + (size_t)(tok0 + l15) * 512;
  const bf16x8* Wf = (const bf16x8*)Wofb;

  f32x4 acc[4];
  #pragma unroll
  for (int cb = 0; cb < 4; ++cb) acc[cb] = f32x4{0.f, 0.f, 0.f, 0.f};

  for (int kb32 = 0; kb32 < 16; ++kb32) {
    bf16x8 af = *(const bf16x8*)(orow + kb32 * 32 + 8 * lg);
    const bf16x8* wrow = Wf + ((size_t)kb32 * 4 + lg) * 512 + colbase + l15;
    #pragma unroll
    for (int cb = 0; cb < 4; ++cb)
      acc[cb] = MFMA(af, wrow[cb * 16], acc[cb]);
  }

  #pragma unroll
  for (int cb = 0; cb < 4; ++cb) {
    int col = colbase + cb * 16 + l15;
    float bv_ = wob[col];
    #pragma unroll
    for (int r = 0; r < 4; ++r) {
      int tok = tok0 + 4 * lg + r;
      out[(size_t)tok * 512 + col] = acc[cb][r] + bv_;
    }
  }
}

// ---------------------------------------------------------------------------
extern "C" void kernel_launch(void* const* d_in, const int* in_sizes, int n_in,
                              void* d_out, int out_size, void* d_ws, size_t ws_size,
                              hipStream_t stream)
{
  const float* x   = (const float*)d_in[0];
  const float* wq  = (const float*)d_in[1];
  const float* bq  = (const float*)d_in[2];
  const float* wk  = (const float*)d_in[3];
  const float* bk  = (const float*)d_in[4];
  const float* wv  = (const float*)d_in[5];
  const float* bv  = (const float*)d_in[6];
  const float* wo  = (const float*)d_in[7];
  const float* wob = (const float*)d_in[8];
  float* out = (float*)d_out;

  // 32MB workspace with live-range aliasing:
  //   [0,8M):   Qb (qkv->attn), then Wof (0.5M, wprep_o->oproj)
  //   [8,16M):  Kb
  //   [16,24M): Vt
  //   [24,32M): Wqkv (1.5M, wprep->qkv), then Ob (attn->oproj)
  const size_t n = (size_t)8192 * 512;
  __bf16* Qb   = (__bf16*)d_ws;
  __bf16* Kb   = Qb + n;
  __bf16* Vt   = Kb + n;
  __bf16* Ob   = Vt + n;
  __bf16* Wqkv = Ob;        // dead before attn writes Ob
  __bf16* Wof  = Qb;        // written after attn (Qb dead), read by oproj

  wprep<<<dim3(16, 3), 256, 0, stream>>>(wq, wk, wv, Wqkv);
  qkv<<<dim3(128, 4), 256, 0, stream>>>(x, Wqkv, bq, bk, bv, Qb, Kb, Vt);
  attn<<<512, 256, 0, stream>>>(Qb, Kb, Vt, Ob);
  wprep<<<dim3(16, 1), 256, 0, stream>>>(wo, wo, wo, Wof);
  oproj<<<dim3(128, 8), 256, 0, stream>>>(Ob, Wof, wob, out);
}

// Round 16
// 135.260 us; speedup vs baseline: 1.0615x; 1.0615x over previous
//
#include <hip/hip_runtime.h>

typedef __bf16 bf16x4 __attribute__((ext_vector_type(4)));
typedef __bf16 bf16x8 __attribute__((ext_vector_type(8)));
typedef float  f32x4  __attribute__((ext_vector_type(4)));

#define MFMA(a, b, c) __builtin_amdgcn_mfma_f32_16x16x32_bf16(a, b, c, 0, 0, 0)

static constexpr int kHeads = 8;
static constexpr int kS     = 4096;

#define CSC 0.18033688011112042f            // log2(e)/8 — folded into Q in qkv
#define LF  (13.287712379549449f / 32.0f)   // log2(10000)/32
#define INV2PI 0.15915494309189535f

__device__ inline float fexp2(float x) {
#if __has_builtin(__builtin_amdgcn_exp2f)
  return __builtin_amdgcn_exp2f(x);
#else
  return __expf(x * 0.6931471805599453f);
#endif
}
__device__ inline float fsin_rev(float rev) {
#if __has_builtin(__builtin_amdgcn_sinf)
  return __builtin_amdgcn_sinf(rev);
#else
  return __sinf(rev * 6.283185307179586f);
#endif
}
__device__ inline float fcos_rev(float rev) {
#if __has_builtin(__builtin_amdgcn_cosf)
  return __builtin_amdgcn_cosf(rev);
#else
  return __cosf(rev * 6.283185307179586f);
#endif
}

// fragment permutation within a 32-element k-block: elem d=16*hi+4*g+e -> slot 8*g+4*hi+e
__device__ inline int perm32(int d) {
  return (((d >> 2) & 3) << 3) + (((d >> 4) & 1) << 2) + (d & 3);
}

__device__ inline void gl16(const void* src, void* lds) {
  __builtin_amdgcn_global_load_lds(
      (const __attribute__((address_space(1))) unsigned int*)src,
      (__attribute__((address_space(3))) unsigned int*)lds, 16, 0, 0);
}

// ---------------------------------------------------------------------------
// wprep: fp32 weights [512 k][512 col] -> fragment-major bf16x8  (r7, proven)
// ---------------------------------------------------------------------------
__global__ __launch_bounds__(256) void wprep(
    const float* __restrict__ w0, const float* __restrict__ w1,
    const float* __restrict__ w2, __bf16* __restrict__ dstb) {
  const int kb32 = blockIdx.x, m = blockIdx.y;
  const float* W = (m == 0) ? w0 : (m == 1) ? w1 : w2;
  bf16x8* dst = (bf16x8*)dstb;
  for (int e = threadIdx.x; e < 2048; e += 256) {
    int lg = e >> 9, col = e & 511;
    bf16x8 v;
    #pragma unroll
    for (int j = 0; j < 8; ++j) {
      int k = kb32 * 32 + 4 * lg + (j & 3) + 16 * (j >> 2);
      v[j] = (__bf16)W[(size_t)k * 512 + col];
    }
    dst[(((size_t)m * 16 + kb32) * 4 + lg) * 512 + col] = v;
  }
}

// ---------------------------------------------------------------------------
// qkv: r12 version (fp32 x, direct W fragments, grid (128,4), 6 tiles/wave)
// ---------------------------------------------------------------------------
__global__ __launch_bounds__(256) void qkv(
    const float* __restrict__ x, const __bf16* __restrict__ Wqkvb,
    const float* __restrict__ bq, const float* __restrict__ bk,
    const float* __restrict__ bv,
    __bf16* __restrict__ Qb, __bf16* __restrict__ Kb, __bf16* __restrict__ Vt)
{
  const int tt   = blockIdx.x;
  const int hp   = blockIdx.y;
  const int wave = threadIdx.x >> 6;
  const int lane = threadIdx.x & 63;
  const int l15  = lane & 15;
  const int lg   = lane >> 4;

  const int tok0 = tt * 64 + wave * 16;
  const float* xrow = x + (size_t)(tok0 + l15) * 512;
  const bf16x8* Wf = (const bf16x8*)Wqkvb;

  f32x4 acc[6][4];   // [m*2+hh][cb]
  #pragma unroll
  for (int t = 0; t < 6; ++t)
    #pragma unroll
    for (int cb = 0; cb < 4; ++cb) acc[t][cb] = f32x4{0.f, 0.f, 0.f, 0.f};

  for (int kb32 = 0; kb32 < 16; ++kb32) {
    f32x4 xa  = *(const f32x4*)(xrow + kb32 * 32 + 4 * lg);
    f32x4 xb4 = *(const f32x4*)(xrow + kb32 * 32 + 16 + 4 * lg);
    bf16x8 af;
    af[0] = (__bf16)xa.x; af[1] = (__bf16)xa.y; af[2] = (__bf16)xa.z; af[3] = (__bf16)xa.w;
    af[4] = (__bf16)xb4.x; af[5] = (__bf16)xb4.y; af[6] = (__bf16)xb4.z; af[7] = (__bf16)xb4.w;
    #pragma unroll
    for (int t = 0; t < 6; ++t) {
      const int m = t >> 1, hh = t & 1;
      const int colb = (hp * 2 + hh) * 64;
      const bf16x8* wrow = Wf + (((size_t)m * 16 + kb32) * 4 + lg) * 512 + colb + l15;
      #pragma unroll
      for (int cb = 0; cb < 4; ++cb)
        acc[t][cb] = MFMA(af, wrow[cb * 16], acc[t][cb]);
    }
  }

  const float frrev0 = fexp2(-LF * (float)l15) * INV2PI;
  const float frrev1 = fexp2(-LF * (float)(16 + l15)) * INV2PI;
  float snv[4][2], csv[4][2];
  #pragma unroll
  for (int r = 0; r < 4; ++r) {
    float sp = (float)((tok0 + 4 * lg + r) & (kS - 1));
    #pragma unroll
    for (int cb = 0; cb < 2; ++cb) {
      float rev = sp * (cb == 0 ? frrev0 : frrev1);
      rev -= floorf(rev);
      snv[r][cb] = fsin_rev(rev);
      csv[r][cb] = fcos_rev(rev);
    }
  }

  #pragma unroll
  for (int t = 0; t < 6; ++t) {
    const int m = t >> 1, hh = t & 1;
    const int h = hp * 2 + hh;
    const float* bias = (m == 0) ? bq : (m == 1) ? bk : bv;
    #pragma unroll
    for (int cb = 0; cb < 4; ++cb) {
      float bv_ = bias[h * 64 + cb * 16 + l15];
      #pragma unroll
      for (int r = 0; r < 4; ++r) acc[t][cb][r] += bv_;
    }
    if (m < 2) {
      #pragma unroll
      for (int r = 0; r < 4; ++r)
        #pragma unroll
        for (int cb = 0; cb < 2; ++cb) {
          float rx = acc[t][cb][r], ry = acc[t][cb + 2][r];
          acc[t][cb][r]     = rx * csv[r][cb] - ry * snv[r][cb];
          acc[t][cb + 2][r] = rx * snv[r][cb] + ry * csv[r][cb];
        }
      if (m == 0) {
        #pragma unroll
        for (int cb = 0; cb < 4; ++cb)
          #pragma unroll
          for (int r = 0; r < 4; ++r) acc[t][cb][r] *= CSC;
      }
    }
    #pragma unroll
    for (int r = 0; r < 4; ++r) {
      int tok = tok0 + 4 * lg + r;
      int b = tok >> 12, srow = tok & (kS - 1);
      size_t bh = (size_t)(b * kHeads + h);
      #pragma unroll
      for (int cb = 0; cb < 4; ++cb) {
        int d = cb * 16 + l15;
        __bf16 v = (__bf16)acc[t][cb][r];
        if (m < 2) {
          int slot = (d & ~31) + perm32(d & 31);
          if (m == 0) Qb[(bh * kS + srow) * 64 + slot] = v;
          else        Kb[(bh * kS + srow) * 64 + slot] = v;
        } else {
          Vt[((size_t)bh * 64 + d) * kS + (srow & ~31) + perm32(srow & 31)] = v;
        }
      }
    }
  }
}

// ---------------------------------------------------------------------------
// attn: q-tile 32 per wave x 8 waves = 256 q-rows/block (grid 256 = 1/CU,
//   16 waves/CU — r15's occupancy fix).  Each K/V LDS fragment feeds 2
//   q-fragments: 32 MFMA per 16 ds_read_b128, halving LDS-read bytes/FLOP.
//   r12 staging + static 3-buffer schedule, PV(t-1) pipelined vs exp(t).
// ---------------------------------------------------------------------------
__global__ __launch_bounds__(512) void attn(
    const __bf16* __restrict__ Qb, const __bf16* __restrict__ Kb,
    const __bf16* __restrict__ Vt, __bf16* __restrict__ Ob)
{
  __shared__ __align__(16) char smem[49152];  // 3 bufs x (K 8KB + V 8KB)

  const int id   = blockIdx.x;                 // [0,256)
  const int bh   = ((id & 7) << 1) | ((id >> 3) & 1);
  const int qt   = id >> 4;                    // [0,16)
  const int tid  = threadIdx.x;
  const int wave = tid >> 6;
  const int lane = tid & 63;
  const int l15  = lane & 15;
  const int lg   = lane >> 4;

  const __bf16* Qp = Qb + (size_t)bh * kS * 64;
  const char*   Kp = (const char*)(Kb + (size_t)bh * kS * 64);
  const char*   Vp = (const char*)(Vt + (size_t)bh * 64 * kS);

  const int q0 = qt * 256 + wave * 32;

  bf16x8 qf[2][2];   // [qi][dh], q-rows q0 + qi*16 + l15
  #pragma unroll
  for (int qi = 0; qi < 2; ++qi)
    #pragma unroll
    for (int dh = 0; dh < 2; ++dh)
      qf[qi][dh] = *(const bf16x8*)(Qp + (size_t)(q0 + qi * 16 + l15) * 64 + dh * 32 + 8 * lg);

  // staging (r12-proven, 512 threads: 1 K-gl16 + 1 V-gl16 each, 8KB+8KB/tile)
  const int srow = tid >> 3;
  const int ssw  = ((tid & 7) * 16) ^ ((srow & 7) << 4);
  const char* ksrc = Kp + (size_t)srow * 128 + ssw;          // +8192/tile
  const char* vsrc = Vp + (size_t)srow * 8192 + ssw;         // +128/tile
  const int   kdst = wave * 1024;                            // wave-uniform
  const int   vdst = 8192 + wave * 1024;

  const int swz = (l15 & 7) << 4;
  const int ka0 = l15 * 128 + ((16 * lg) ^ swz);
  const int ka1 = l15 * 128 + ((64 + 16 * lg) ^ swz);
  const int va0 = 8192 + ka0;
  const int va1 = 8192 + ka1;

  const f32x4 kZero = f32x4{0.f, 0.f, 0.f, 0.f};

  char* const B0 = smem;
  char* const B1 = smem + 16384;
  char* const B2 = smem + 32768;

  f32x4 oacc[2][4];   // [qi][db]
  #pragma unroll
  for (int qi = 0; qi < 2; ++qi)
    #pragma unroll
    for (int db = 0; db < 4; ++db) oacc[qi][db] = kZero;
  float lp0 = 0.f, lp1 = 0.f;
  bf16x8 paP[2][2], paC[2][2];   // [qi][half]

  auto stage = [&](char* sb) {
    gl16(ksrc, sb + kdst);
    gl16(vsrc, sb + vdst);
    ksrc += 8192; vsrc += 128;
  };

  // prologue: stage tile 0 -> B0; sync; stage tile 1 -> B1; QK(0)+exp
  stage(B0);
  __syncthreads();
  stage(B1);
  {
    f32x4 sa[2][4];
    __builtin_amdgcn_s_setprio(1);
    #pragma unroll
    for (int kh = 0; kh < 4; ++kh) {
      bf16x8 kf0 = *(const bf16x8*)(B0 + kh * 2048 + ka0);
      bf16x8 kf1 = *(const bf16x8*)(B0 + kh * 2048 + ka1);
      #pragma unroll
      for (int qi = 0; qi < 2; ++qi) {
        sa[qi][kh] = MFMA(kf0, qf[qi][0], kZero);
        sa[qi][kh] = MFMA(kf1, qf[qi][1], sa[qi][kh]);
      }
    }
    __builtin_amdgcn_s_setprio(0);
    #pragma unroll
    for (int qi = 0; qi < 2; ++qi)
      #pragma unroll
      for (int kh = 0; kh < 4; ++kh)
        #pragma unroll
        for (int rr = 0; rr < 4; ++rr) {
          float p = fexp2(sa[qi][kh][rr]);
          if (qi == 0) lp0 += p; else lp1 += p;
          paP[qi][kh >> 1][(kh & 1) * 4 + rr] = (__bf16)p;
        }
  }

  auto body = [&](const char* sbP, const char* sbC, char* sbN, bool doStage) {
    __syncthreads();    // stage(t) complete; buf(t-3) reads long done
    if (doStage) stage(sbN);
    f32x4 sa[2][4];
    __builtin_amdgcn_s_setprio(1);
    #pragma unroll
    for (int kh = 0; kh < 4; ++kh) {
      bf16x8 kf0 = *(const bf16x8*)(sbC + kh * 2048 + ka0);
      bf16x8 kf1 = *(const bf16x8*)(sbC + kh * 2048 + ka1);
      #pragma unroll
      for (int qi = 0; qi < 2; ++qi) {
        sa[qi][kh] = MFMA(kf0, qf[qi][0], kZero);
        sa[qi][kh] = MFMA(kf1, qf[qi][1], sa[qi][kh]);
      }
    }
    // PV(t-1): independent of sa — grinds MFMA pipe while exp(t) runs on VALU
    #pragma unroll
    for (int db = 0; db < 4; ++db) {
      bf16x8 vf0 = *(const bf16x8*)(sbP + db * 2048 + va0);
      bf16x8 vf1 = *(const bf16x8*)(sbP + db * 2048 + va1);
      #pragma unroll
      for (int qi = 0; qi < 2; ++qi) {
        oacc[qi][db] = MFMA(vf0, paP[qi][0], oacc[qi][db]);
        oacc[qi][db] = MFMA(vf1, paP[qi][1], oacc[qi][db]);
      }
    }
    __builtin_amdgcn_s_setprio(0);
    #pragma unroll
    for (int qi = 0; qi < 2; ++qi)
      #pragma unroll
      for (int kh = 0; kh < 4; ++kh)
        #pragma unroll
        for (int rr = 0; rr < 4; ++rr) {
          float p = fexp2(sa[qi][kh][rr]);
          if (qi == 0) lp0 += p; else lp1 += p;
          paC[qi][kh >> 1][(kh & 1) * 4 + rr] = (__bf16)p;
        }
    #pragma unroll
    for (int qi = 0; qi < 2; ++qi) {
      paP[qi][0] = paC[qi][0];
      paP[qi][1] = paC[qi][1];
    }
  };

  // steady state: t = 1..60 (20 groups of 3) + peeled tail t = 61,62,63
  for (int g = 0; g < 20; ++g) {
    body(B0, B1, B2, true);
    body(B1, B2, B0, true);
    body(B2, B0, B1, true);
  }
  body(B0, B1, B2, true);
  body(B1, B2, B0, true);
  body(B2, B0, B1, false);

  // epilogue: PV(63) from B0
  {
    __builtin_amdgcn_s_setprio(1);
    #pragma unroll
    for (int db = 0; db < 4; ++db) {
      bf16x8 vf0 = *(const bf16x8*)(B0 + db * 2048 + va0);
      bf16x8 vf1 = *(const bf16x8*)(B0 + db * 2048 + va1);
      #pragma unroll
      for (int qi = 0; qi < 2; ++qi) {
        oacc[qi][db] = MFMA(vf0, paP[qi][0], oacc[qi][db]);
        oacc[qi][db] = MFMA(vf1, paP[qi][1], oacc[qi][db]);
      }
    }
    __builtin_amdgcn_s_setprio(0);
  }

  const int b = bh >> 3, h = bh & 7;
  #pragma unroll
  for (int qi = 0; qi < 2; ++qi) {
    float lrun = (qi == 0) ? lp0 : lp1;
    lrun += __shfl_xor(lrun, 16);
    lrun += __shfl_xor(lrun, 32);
    float inv = 1.0f / lrun;
    const int q = q0 + qi * 16 + l15;
    #pragma unroll
    for (int db = 0; db < 4; ++db) {
      bf16x4 o4;
      #pragma unroll
      for (int rr = 0; rr < 4; ++rr) o4[rr] = (__bf16)(oacc[qi][db][rr] * inv);
      size_t e = ((size_t)(b * kS + q)) * 512 + h * 64 + (db >> 1) * 32 + 8 * lg + 4 * (db & 1);
      *(bf16x4*)(Ob + e) = o4;
    }
  }
}

// ---------------------------------------------------------------------------
// oproj: out[t][m] = sum_c Ob[t][c] * wo[c][m] + wo_b[m]   (fp32 out)  (r7)
// ---------------------------------------------------------------------------
__global__ __launch_bounds__(256) void oproj(
    const __bf16* __restrict__ Ob, const __bf16* __restrict__ Wofb,
    const float* __restrict__ wob, float* __restrict__ out)
{
  const int tt   = blockIdx.x;
  const int ct   = blockIdx.y;
  const int wave = threadIdx.x >> 6;
  const int lane = threadIdx.x & 63;
  const int l15  = lane & 15;
  const int lg   = lane >> 4;

  const int tok0 = tt * 64 + wave * 16;
  const int colbase = ct * 64;
  const __bf16* orow = Ob + (size_t)(tok0 + l15) * 512;
  const bf16x8* Wf = (const bf16x8*)Wofb;

  f32x4 acc[4];
  #pragma unroll
  for (int cb = 0; cb < 4; ++cb) acc[cb] = f32x4{0.f, 0.f, 0.f, 0.f};

  for (int kb32 = 0; kb32 < 16; ++kb32) {
    bf16x8 af = *(const bf16x8*)(orow + kb32 * 32 + 8 * lg);
    const bf16x8* wrow = Wf + ((size_t)kb32 * 4 + lg) * 512 + colbase + l15;
    #pragma unroll
    for (int cb = 0; cb < 4; ++cb)
      acc[cb] = MFMA(af, wrow[cb * 16], acc[cb]);
  }

  #pragma unroll
  for (int cb = 0; cb < 4; ++cb) {
    int col = colbase + cb * 16 + l15;
    float bv_ = wob[col];
    #pragma unroll
    for (int r = 0; r < 4; ++r) {
      int tok = tok0 + 4 * lg + r;
      out[(size_t)tok * 512 + col] = acc[cb][r] + bv_;
    }
  }
}

// ---------------------------------------------------------------------------
extern "C" void kernel_launch(void* const* d_in, const int* in_sizes, int n_in,
                              void* d_out, int out_size, void* d_ws, size_t ws_size,
                              hipStream_t stream)
{
  const float* x   = (const float*)d_in[0];
  const float* wq  = (const float*)d_in[1];
  const float* bq  = (const float*)d_in[2];
  const float* wk  = (const float*)d_in[3];
  const float* bk  = (const float*)d_in[4];
  const float* wv  = (const float*)d_in[5];
  const float* bv  = (const float*)d_in[6];
  const float* wo  = (const float*)d_in[7];
  const float* wob = (const float*)d_in[8];
  float* out = (float*)d_out;

  // 32MB workspace with live-range aliasing:
  //   [0,8M):   Qb (qkv->attn), then Wof (0.5M, wprep_o->oproj)
  //   [8,16M):  Kb
  //   [16,24M): Vt
  //   [24,32M): Wqkv (1.5M, wprep->qkv), then Ob (attn->oproj)
  const size_t n = (size_t)8192 * 512;
  __bf16* Qb   = (__bf16*)d_ws;
  __bf16* Kb   = Qb + n;
  __bf16* Vt   = Kb + n;
  __bf16* Ob   = Vt + n;
  __bf16* Wqkv = Ob;        // dead before attn writes Ob
  __bf16* Wof  = Qb;        // written after attn (Qb dead), read by oproj

  wprep<<<dim3(16, 3), 256, 0, stream>>>(wq, wk, wv, Wqkv);
  qkv<<<dim3(128, 4), 256, 0, stream>>>(x, Wqkv, bq, bk, bv, Qb, Kb, Vt);
  attn<<<256, 512, 0, stream>>>(Qb, Kb, Vt, Ob);
  wprep<<<dim3(16, 1), 256, 0, stream>>>(wo, wo, wo, Wof);
  oproj<<<dim3(128, 8), 256, 0, stream>>>(Ob, Wof, wob, out);
}